// Round 1
// baseline (372.713 us; speedup 1.0000x reference)
//
#include <hip/hip_runtime.h>

#define N_NODES_C 100000
#define N_EDGES_C 1600000
#define IN_F 128
#define OUT_F 64

#define BIN_SHIFT 9
#define BIN_SZ    512                                  // nodes per bin
#define NBIN      ((N_NODES_C + BIN_SZ - 1) / BIN_SZ)  // 196
#define NCHUNK    256
#define CH        (N_EDGES_C / NCHUNK)                 // 6250 exactly

// ---------------- GEMM: h[n][64] = x[n][128] @ W[64][128]^T + b ----------------
__global__ __launch_bounds__(256) void gemm_kernel(
    const float* __restrict__ x, const float* __restrict__ W,
    const float* __restrict__ bias, float* __restrict__ h, int n) {
  __shared__ float Wt[IN_F * OUT_F];   // [k][o], stride 64, 32 KB
  const int t = threadIdx.x;
  {
    const int o = t & 63;
    const int k4base = t >> 6;
    const float4* Wrow = (const float4*)(W + o * IN_F);
#pragma unroll
    for (int i = 0; i < 8; ++i) {
      int k4 = k4base + i * 4;
      float4 v = Wrow[k4];
      int k = k4 * 4;
      Wt[(k + 0) * OUT_F + o] = v.x;
      Wt[(k + 1) * OUT_F + o] = v.y;
      Wt[(k + 2) * OUT_F + o] = v.z;
      Wt[(k + 3) * OUT_F + o] = v.w;
    }
  }
  __syncthreads();

  const int tx = t & 15;
  const int ty = t >> 4;
  const int node0 = blockIdx.x * 64 + ty * 4;

  bool v0 = node0 + 0 < n, v1 = node0 + 1 < n, v2 = node0 + 2 < n, v3 = node0 + 3 < n;
  const float4* xr0 = (const float4*)(x + (size_t)(v0 ? node0 + 0 : 0) * IN_F);
  const float4* xr1 = (const float4*)(x + (size_t)(v1 ? node0 + 1 : 0) * IN_F);
  const float4* xr2 = (const float4*)(x + (size_t)(v2 ? node0 + 2 : 0) * IN_F);
  const float4* xr3 = (const float4*)(x + (size_t)(v3 ? node0 + 3 : 0) * IN_F);

  float4 acc0 = make_float4(0.f, 0.f, 0.f, 0.f);
  float4 acc1 = acc0, acc2 = acc0, acc3 = acc0;
  const float4* Wt4 = (const float4*)Wt;

#pragma unroll 2
  for (int kc = 0; kc < 32; ++kc) {
    float4 xv0 = xr0[kc];
    float4 xv1 = xr1[kc];
    float4 xv2 = xr2[kc];
    float4 xv3 = xr3[kc];
    float4 w0 = Wt4[(kc * 4 + 0) * 16 + tx];
    float4 w1 = Wt4[(kc * 4 + 1) * 16 + tx];
    float4 w2 = Wt4[(kc * 4 + 2) * 16 + tx];
    float4 w3 = Wt4[(kc * 4 + 3) * 16 + tx];
#define FMA4(A, XV)                                            \
    A.x += XV.x * w0.x + XV.y * w1.x + XV.z * w2.x + XV.w * w3.x; \
    A.y += XV.x * w0.y + XV.y * w1.y + XV.z * w2.y + XV.w * w3.y; \
    A.z += XV.x * w0.z + XV.y * w1.z + XV.z * w2.z + XV.w * w3.z; \
    A.w += XV.x * w0.w + XV.y * w1.w + XV.z * w2.w + XV.w * w3.w;
    FMA4(acc0, xv0)
    FMA4(acc1, xv1)
    FMA4(acc2, xv2)
    FMA4(acc3, xv3)
#undef FMA4
  }

  const float4 bv = ((const float4*)bias)[tx];
  acc0.x += bv.x; acc0.y += bv.y; acc0.z += bv.z; acc0.w += bv.w;
  acc1.x += bv.x; acc1.y += bv.y; acc1.z += bv.z; acc1.w += bv.w;
  acc2.x += bv.x; acc2.y += bv.y; acc2.z += bv.z; acc2.w += bv.w;
  acc3.x += bv.x; acc3.y += bv.y; acc3.z += bv.z; acc3.w += bv.w;

  if (v0) ((float4*)(h + (size_t)(node0 + 0) * OUT_F))[tx] = acc0;
  if (v1) ((float4*)(h + (size_t)(node0 + 1) * OUT_F))[tx] = acc1;
  if (v2) ((float4*)(h + (size_t)(node0 + 2) * OUT_F))[tx] = acc2;
  if (v3) ((float4*)(h + (size_t)(node0 + 3) * OUT_F))[tx] = acc3;
}

// ---------------- CSR build: LDS-binned counting sort ----------------
// Phase 1: per-chunk LDS histogram over 196 bins.
__global__ __launch_bounds__(256) void hist_kernel(
    const int* __restrict__ dst, int* __restrict__ hist) {
  __shared__ int h[NBIN];
  const int t = threadIdx.x;
  for (int i = t; i < NBIN; i += 256) h[i] = 0;
  __syncthreads();
  const int e0 = blockIdx.x * CH;
  for (int i = t; i < CH; i += 256)
    atomicAdd(&h[dst[e0 + i] >> BIN_SHIFT], 1);
  __syncthreads();
  for (int i = t; i < NBIN; i += 256)
    hist[i * NCHUNK + blockIdx.x] = h[i];      // bin-major layout
}

#define RB 256
__global__ __launch_bounds__(RB) void reduce_kernel(
    const int* __restrict__ v, int* __restrict__ blockSums, int n) {
  __shared__ int s[RB];
  int i = blockIdx.x * RB + threadIdx.x;
  s[threadIdx.x] = (i < n) ? v[i] : 0;
  __syncthreads();
  for (int off = RB / 2; off > 0; off >>= 1) {
    if (threadIdx.x < off) s[threadIdx.x] += s[threadIdx.x + off];
    __syncthreads();
  }
  if (threadIdx.x == 0) blockSums[blockIdx.x] = s[0];
}

__global__ __launch_bounds__(512) void scan_partials_kernel(
    const int* __restrict__ blockSums, int* __restrict__ blockOffs, int nb,
    int* __restrict__ total_out) {
  __shared__ int s[512];
  int t = threadIdx.x;
  int v = (t < nb) ? blockSums[t] : 0;
  s[t] = v;
  __syncthreads();
  for (int off = 1; off < 512; off <<= 1) {
    int u = (t >= off) ? s[t - off] : 0;
    __syncthreads();
    s[t] += u;
    __syncthreads();
  }
  if (t < nb) blockOffs[t] = s[t] - v;      // exclusive
  if (t == 511) *total_out = s[511];        // == E (scratch)
}

// Final: exclusive scan of hist -> soff (same layout); binStart[b] = soff[b*NCHUNK].
// One block per bin-row (256 threads == NCHUNK).
__global__ __launch_bounds__(RB) void scan_final_kernel(
    const int* __restrict__ hist, const int* __restrict__ blockOffs,
    int* __restrict__ soff, int* __restrict__ binStart, int n) {
  __shared__ int s[RB];
  int i = blockIdx.x * RB + threadIdx.x;
  int v = (i < n) ? hist[i] : 0;
  s[threadIdx.x] = v;
  __syncthreads();
  for (int off = 1; off < RB; off <<= 1) {
    int u = (threadIdx.x >= off) ? s[threadIdx.x - off] : 0;
    __syncthreads();
    s[threadIdx.x] += u;
    __syncthreads();
  }
  if (i < n) {
    int ex = blockOffs[blockIdx.x] + s[threadIdx.x] - v;
    soff[i] = ex;
    if (threadIdx.x == 0) binStart[blockIdx.x] = ex;   // chunk 0 of this bin
  }
}

// Phase 2: re-read chunk, append records at LDS-cursor positions.
// Each (block,bin) run is a contiguous burst written by ONE CU -> dense writebacks.
__global__ __launch_bounds__(256) void binscatter_kernel(
    const int* __restrict__ src, const int* __restrict__ dst,
    const float* __restrict__ w, const int* __restrict__ soff,
    int* __restrict__ stage_d, int2* __restrict__ stage_sw) {
  __shared__ int lcur[NBIN];
  const int t = threadIdx.x;
  const int c = blockIdx.x;
  for (int i = t; i < NBIN; i += 256) lcur[i] = soff[i * NCHUNK + c];
  __syncthreads();
  const int e0 = c * CH;
  for (int i = t; i < CH; i += 256) {
    int e = e0 + i;
    int d = dst[e];
    int p = atomicAdd(&lcur[d >> BIN_SHIFT], 1);
    stage_d[p]  = d;
    stage_sw[p] = make_int2(src[e] * OUT_F, __float_as_int(w[e]));
  }
}

// Phase 3: one block per bin. LDS count -> LDS scan (row_ptr for free) ->
// place records at exact CSR slots. All traffic within the bin's ~65KB span.
__global__ __launch_bounds__(BIN_SZ) void place_kernel(
    const int* __restrict__ binStart, const int* __restrict__ stage_d,
    const int2* __restrict__ stage_sw, int* __restrict__ row_ptr,
    int2* __restrict__ edges, int n) {
  __shared__ int lcount[BIN_SZ];
  __shared__ int s[BIN_SZ];
  __shared__ int lcur[BIN_SZ];
  const int t = threadIdx.x;
  const int b = blockIdx.x;
  const int base = binStart[b];
  const int end  = (b == NBIN - 1) ? N_EDGES_C : binStart[b + 1];
  const int node0 = b << BIN_SHIFT;

  lcount[t] = 0;
  __syncthreads();
  for (int i = base + t; i < end; i += BIN_SZ)
    atomicAdd(&lcount[stage_d[i] - node0], 1);
  __syncthreads();

  int v = lcount[t];
  s[t] = v;
  __syncthreads();
  for (int off = 1; off < BIN_SZ; off <<= 1) {
    int u = (t >= off) ? s[t - off] : 0;
    __syncthreads();
    s[t] += u;
    __syncthreads();
  }
  int ex = base + s[t] - v;       // exclusive CSR offset for node node0+t
  int node = node0 + t;
  if (node < n) row_ptr[node] = ex;
  lcur[t] = ex;
  __syncthreads();

  for (int i = base + t; i < end; i += BIN_SZ) {
    int d = stage_d[i];
    int p = atomicAdd(&lcur[d - node0], 1);
    edges[p] = stage_sw[i];
  }
  if (b == NBIN - 1 && t == 0) row_ptr[n] = N_EDGES_C;
}

// ---------------- SpMM hop ----------------
// 16 lanes per node (lane fl owns features [4fl..4fl+3]), 4 nodes per wave,
// 4-deep edge unroll => 16 independent 256B row-gathers in flight per wave.
// No cross-lane reduction; every lane stores its own accumulator.
__global__ __launch_bounds__(256) void spmm_kernel(
    const int* __restrict__ row_ptr, const int2* __restrict__ edges,
    const float* __restrict__ hin, float* __restrict__ hout, int n) {
  const int node = blockIdx.x * 16 + (threadIdx.x >> 4);
  const int fl   = threadIdx.x & 15;     // feature quad
  if (node >= n) return;
  const int beg = row_ptr[node];
  const int end = row_ptr[node + 1];

  float4 acc = make_float4(0.f, 0.f, 0.f, 0.f);
  int j = beg;
  for (; j + 3 < end; j += 4) {
    int2 e0 = edges[j + 0];
    int2 e1 = edges[j + 1];
    int2 e2 = edges[j + 2];
    int2 e3 = edges[j + 3];
    float4 h0 = ((const float4*)(hin + e0.x))[fl];
    float4 h1 = ((const float4*)(hin + e1.x))[fl];
    float4 h2 = ((const float4*)(hin + e2.x))[fl];
    float4 h3 = ((const float4*)(hin + e3.x))[fl];
    float w0 = __int_as_float(e0.y);
    float w1 = __int_as_float(e1.y);
    float w2 = __int_as_float(e2.y);
    float w3 = __int_as_float(e3.y);
    acc.x += w0 * h0.x + w1 * h1.x + w2 * h2.x + w3 * h3.x;
    acc.y += w0 * h0.y + w1 * h1.y + w2 * h2.y + w3 * h3.y;
    acc.z += w0 * h0.z + w1 * h1.z + w2 * h2.z + w3 * h3.z;
    acc.w += w0 * h0.w + w1 * h1.w + w2 * h2.w + w3 * h3.w;
  }
  for (; j < end; ++j) {
    int2 e = edges[j];
    float4 hv = ((const float4*)(hin + e.x))[fl];
    float w = __int_as_float(e.y);
    acc.x += w * hv.x;
    acc.y += w * hv.y;
    acc.z += w * hv.z;
    acc.w += w * hv.w;
  }

  ((float4*)(hout + (size_t)node * OUT_F))[fl] = acc;
}

extern "C" void kernel_launch(void* const* d_in, const int* in_sizes, int n_in,
                              void* d_out, int out_size, void* d_ws, size_t ws_size,
                              hipStream_t stream) {
  const float* x    = (const float*)d_in[0];
  const int*   ei   = (const int*)d_in[1];   // int32 (harness materializes ints as int32)
  const float* ew   = (const float*)d_in[2];
  const float* W    = (const float*)d_in[3];
  const float* bias = (const float*)d_in[4];
  float* out = (float*)d_out;

  const int N = N_NODES_C;
  const int E = N_EDGES_C;
  const int* src = ei;
  const int* dst = ei + E;
  const int NH = NBIN * NCHUNK;        // 50176 hist entries
  const int NRB = NH / RB;             // 196 reduce blocks

  char* p = (char*)d_ws;
  auto carve = [&](size_t bytes) {
    void* r = (void*)p;
    p += (bytes + 255) & ~(size_t)255;
    return r;
  };
  float* hA        = (float*)carve((size_t)N * OUT_F * 4);
  int*   row_ptr   = (int*)  carve((size_t)(N + 1) * 4);
  int2*  edges     = (int2*) carve((size_t)E * 8);
  int*   hist      = (int*)  carve((size_t)NH * 4);
  int*   soff      = (int*)  carve((size_t)NH * 4);
  int*   blockSums = (int*)  carve((size_t)NRB * 4);
  int*   blockOffs = (int*)  carve((size_t)NRB * 4);
  int*   binStart  = (int*)  carve((size_t)(NBIN + 1) * 4);  // +1 scratch for total

  // staging in d_out (free scratch until spmm hop 1): sw 12.8MB + d 6.4MB
  int2* stage_sw = (int2*)d_out;
  int*  stage_d  = (int*)((char*)d_out + (size_t)E * 8);

  // CSR build (no global atomics)
  hist_kernel         <<<NCHUNK, 256, 0, stream>>>(dst, hist);
  reduce_kernel       <<<NRB, RB, 0, stream>>>(hist, blockSums, NH);
  scan_partials_kernel<<<1, 512, 0, stream>>>(blockSums, blockOffs, NRB, &binStart[NBIN]);
  scan_final_kernel   <<<NRB, RB, 0, stream>>>(hist, blockOffs, soff, binStart, NH);
  binscatter_kernel   <<<NCHUNK, 256, 0, stream>>>(src, dst, ew, soff, stage_d, stage_sw);
  place_kernel        <<<NBIN, BIN_SZ, 0, stream>>>(binStart, stage_d, stage_sw,
                                                    row_ptr, edges, N);

  // h0 = x @ W^T + b
  gemm_kernel<<<(N + 63) / 64, 256, 0, stream>>>(x, W, bias, hA, N);

  // 3 hops, ping-pong hA <-> out
  spmm_kernel<<<(N + 15) / 16, 256, 0, stream>>>(row_ptr, edges, hA, out, N);
  spmm_kernel<<<(N + 15) / 16, 256, 0, stream>>>(row_ptr, edges, out, hA, N);
  spmm_kernel<<<(N + 15) / 16, 256, 0, stream>>>(row_ptr, edges, hA, out, N);
}

// Round 2
// 303.627 us; speedup vs baseline: 1.2275x; 1.2275x over previous
//
#include <hip/hip_runtime.h>
#include <hip/hip_fp16.h>

#define N_NODES_C 100000
#define N_EDGES_C 1600000
#define IN_F 128
#define OUT_F 64

#define BIN_SHIFT 9
#define BIN_SZ    512                                  // nodes per bin
#define NBIN      ((N_NODES_C + BIN_SZ - 1) / BIN_SZ)  // 196
#define NCHUNK    256
#define CH        (N_EDGES_C / NCHUNK)                 // 6250 exactly

// ---------------- GEMM: h[n][64] = fp16(x[n][128] @ W[64][128]^T + b) ----------------
__global__ __launch_bounds__(256) void gemm_kernel(
    const float* __restrict__ x, const float* __restrict__ W,
    const float* __restrict__ bias, __half* __restrict__ h, int n) {
  __shared__ float Wt[IN_F * OUT_F];   // [k][o], stride 64, 32 KB
  const int t = threadIdx.x;
  {
    const int o = t & 63;
    const int k4base = t >> 6;
    const float4* Wrow = (const float4*)(W + o * IN_F);
#pragma unroll
    for (int i = 0; i < 8; ++i) {
      int k4 = k4base + i * 4;
      float4 v = Wrow[k4];
      int k = k4 * 4;
      Wt[(k + 0) * OUT_F + o] = v.x;
      Wt[(k + 1) * OUT_F + o] = v.y;
      Wt[(k + 2) * OUT_F + o] = v.z;
      Wt[(k + 3) * OUT_F + o] = v.w;
    }
  }
  __syncthreads();

  const int tx = t & 15;
  const int ty = t >> 4;
  const int node0 = blockIdx.x * 64 + ty * 4;

  bool v0 = node0 + 0 < n, v1 = node0 + 1 < n, v2 = node0 + 2 < n, v3 = node0 + 3 < n;
  const float4* xr0 = (const float4*)(x + (size_t)(v0 ? node0 + 0 : 0) * IN_F);
  const float4* xr1 = (const float4*)(x + (size_t)(v1 ? node0 + 1 : 0) * IN_F);
  const float4* xr2 = (const float4*)(x + (size_t)(v2 ? node0 + 2 : 0) * IN_F);
  const float4* xr3 = (const float4*)(x + (size_t)(v3 ? node0 + 3 : 0) * IN_F);

  float4 acc0 = make_float4(0.f, 0.f, 0.f, 0.f);
  float4 acc1 = acc0, acc2 = acc0, acc3 = acc0;
  const float4* Wt4 = (const float4*)Wt;

#pragma unroll 2
  for (int kc = 0; kc < 32; ++kc) {
    float4 xv0 = xr0[kc];
    float4 xv1 = xr1[kc];
    float4 xv2 = xr2[kc];
    float4 xv3 = xr3[kc];
    float4 w0 = Wt4[(kc * 4 + 0) * 16 + tx];
    float4 w1 = Wt4[(kc * 4 + 1) * 16 + tx];
    float4 w2 = Wt4[(kc * 4 + 2) * 16 + tx];
    float4 w3 = Wt4[(kc * 4 + 3) * 16 + tx];
#define FMA4(A, XV)                                            \
    A.x += XV.x * w0.x + XV.y * w1.x + XV.z * w2.x + XV.w * w3.x; \
    A.y += XV.x * w0.y + XV.y * w1.y + XV.z * w2.y + XV.w * w3.y; \
    A.z += XV.x * w0.z + XV.y * w1.z + XV.z * w2.z + XV.w * w3.z; \
    A.w += XV.x * w0.w + XV.y * w1.w + XV.z * w2.w + XV.w * w3.w;
    FMA4(acc0, xv0)
    FMA4(acc1, xv1)
    FMA4(acc2, xv2)
    FMA4(acc3, xv3)
#undef FMA4
  }

  const float4 bv = ((const float4*)bias)[tx];
  acc0.x += bv.x; acc0.y += bv.y; acc0.z += bv.z; acc0.w += bv.w;
  acc1.x += bv.x; acc1.y += bv.y; acc1.z += bv.z; acc1.w += bv.w;
  acc2.x += bv.x; acc2.y += bv.y; acc2.z += bv.z; acc2.w += bv.w;
  acc3.x += bv.x; acc3.y += bv.y; acc3.z += bv.z; acc3.w += bv.w;

#define STORE16(A, NODE, VALID)                                         \
  if (VALID) {                                                          \
    union { __half2 h2[2]; uint2 u; } pk;                               \
    pk.h2[0] = __floats2half2_rn(A.x, A.y);                             \
    pk.h2[1] = __floats2half2_rn(A.z, A.w);                             \
    ((uint2*)((char*)h + (size_t)(NODE) * 128))[tx] = pk.u;             \
  }
  STORE16(acc0, node0 + 0, v0)
  STORE16(acc1, node0 + 1, v1)
  STORE16(acc2, node0 + 2, v2)
  STORE16(acc3, node0 + 3, v3)
#undef STORE16
}

// ---------------- CSR build: LDS-binned counting sort ----------------
__global__ __launch_bounds__(256) void hist_kernel(
    const int* __restrict__ dst, int* __restrict__ hist) {
  __shared__ int h[NBIN];
  const int t = threadIdx.x;
  for (int i = t; i < NBIN; i += 256) h[i] = 0;
  __syncthreads();
  const int e0 = blockIdx.x * CH;
  for (int i = t; i < CH; i += 256)
    atomicAdd(&h[dst[e0 + i] >> BIN_SHIFT], 1);
  __syncthreads();
  for (int i = t; i < NBIN; i += 256)
    hist[i * NCHUNK + blockIdx.x] = h[i];      // bin-major layout
}

#define RB 256
__global__ __launch_bounds__(RB) void reduce_kernel(
    const int* __restrict__ v, int* __restrict__ blockSums, int n) {
  __shared__ int s[RB];
  int i = blockIdx.x * RB + threadIdx.x;
  s[threadIdx.x] = (i < n) ? v[i] : 0;
  __syncthreads();
  for (int off = RB / 2; off > 0; off >>= 1) {
    if (threadIdx.x < off) s[threadIdx.x] += s[threadIdx.x + off];
    __syncthreads();
  }
  if (threadIdx.x == 0) blockSums[blockIdx.x] = s[0];
}

__global__ __launch_bounds__(512) void scan_partials_kernel(
    const int* __restrict__ blockSums, int* __restrict__ blockOffs, int nb,
    int* __restrict__ total_out) {
  __shared__ int s[512];
  int t = threadIdx.x;
  int v = (t < nb) ? blockSums[t] : 0;
  s[t] = v;
  __syncthreads();
  for (int off = 1; off < 512; off <<= 1) {
    int u = (t >= off) ? s[t - off] : 0;
    __syncthreads();
    s[t] += u;
    __syncthreads();
  }
  if (t < nb) blockOffs[t] = s[t] - v;      // exclusive
  if (t == 511) *total_out = s[511];        // == E (scratch)
}

__global__ __launch_bounds__(RB) void scan_final_kernel(
    const int* __restrict__ hist, const int* __restrict__ blockOffs,
    int* __restrict__ soff, int* __restrict__ binStart, int n) {
  __shared__ int s[RB];
  int i = blockIdx.x * RB + threadIdx.x;
  int v = (i < n) ? hist[i] : 0;
  s[threadIdx.x] = v;
  __syncthreads();
  for (int off = 1; off < RB; off <<= 1) {
    int u = (threadIdx.x >= off) ? s[threadIdx.x - off] : 0;
    __syncthreads();
    s[threadIdx.x] += u;
    __syncthreads();
  }
  if (i < n) {
    int ex = blockOffs[blockIdx.x] + s[threadIdx.x] - v;
    soff[i] = ex;
    if (threadIdx.x == 0) binStart[blockIdx.x] = ex;   // chunk 0 of this bin
  }
}

__global__ __launch_bounds__(256) void binscatter_kernel(
    const int* __restrict__ src, const int* __restrict__ dst,
    const float* __restrict__ w, const int* __restrict__ soff,
    int* __restrict__ stage_d, int2* __restrict__ stage_sw) {
  __shared__ int lcur[NBIN];
  const int t = threadIdx.x;
  const int c = blockIdx.x;
  for (int i = t; i < NBIN; i += 256) lcur[i] = soff[i * NCHUNK + c];
  __syncthreads();
  const int e0 = c * CH;
  for (int i = t; i < CH; i += 256) {
    int e = e0 + i;
    int d = dst[e];
    int p = atomicAdd(&lcur[d >> BIN_SHIFT], 1);
    stage_d[p]  = d;
    stage_sw[p] = make_int2(src[e] * OUT_F, __float_as_int(w[e]));
  }
}

__global__ __launch_bounds__(BIN_SZ) void place_kernel(
    const int* __restrict__ binStart, const int* __restrict__ stage_d,
    const int2* __restrict__ stage_sw, int* __restrict__ row_ptr,
    int2* __restrict__ edges, int n) {
  __shared__ int lcount[BIN_SZ];
  __shared__ int s[BIN_SZ];
  __shared__ int lcur[BIN_SZ];
  const int t = threadIdx.x;
  const int b = blockIdx.x;
  const int base = binStart[b];
  const int end  = (b == NBIN - 1) ? N_EDGES_C : binStart[b + 1];
  const int node0 = b << BIN_SHIFT;

  lcount[t] = 0;
  __syncthreads();
  for (int i = base + t; i < end; i += BIN_SZ)
    atomicAdd(&lcount[stage_d[i] - node0], 1);
  __syncthreads();

  int v = lcount[t];
  s[t] = v;
  __syncthreads();
  for (int off = 1; off < BIN_SZ; off <<= 1) {
    int u = (t >= off) ? s[t - off] : 0;
    __syncthreads();
    s[t] += u;
    __syncthreads();
  }
  int ex = base + s[t] - v;       // exclusive CSR offset for node node0+t
  int node = node0 + t;
  if (node < n) row_ptr[node] = ex;
  lcur[t] = ex;
  __syncthreads();

  for (int i = base + t; i < end; i += BIN_SZ) {
    int d = stage_d[i];
    int p = atomicAdd(&lcur[d - node0], 1);
    edges[p] = stage_sw[i];
  }
  if (b == NBIN - 1 && t == 0) row_ptr[n] = N_EDGES_C;
}

// ---------------- SpMM hop (fp16 rows) ----------------
// 8 lanes per node (lane fl owns features [8fl..8fl+7]), 8 nodes per wave,
// 4-deep edge unroll. Each gather instr: 8 rows x 128B (2 cache lines each).
// e.x = src*64 (element offset); fp16 row = 128 B. Accumulate fp32.
__device__ inline void fma8_h(float* acc, uint4 r, float w) {
  unsigned u[4] = {r.x, r.y, r.z, r.w};
#pragma unroll
  for (int q = 0; q < 4; ++q) {
    __half2 h2 = *reinterpret_cast<__half2*>(&u[q]);
    float2 f = __half22float2(h2);
    acc[2 * q + 0] += w * f.x;
    acc[2 * q + 1] += w * f.y;
  }
}

template <int OUT32>
__global__ __launch_bounds__(256) void spmm16_kernel(
    const int* __restrict__ row_ptr, const int2* __restrict__ edges,
    const __half* __restrict__ hin, void* __restrict__ hout, int n) {
  const int node = blockIdx.x * 32 + (threadIdx.x >> 3);
  const int fl   = threadIdx.x & 7;     // feature octet
  if (node >= n) return;
  const int beg = row_ptr[node];
  const int end = row_ptr[node + 1];

  float acc[8] = {0.f, 0.f, 0.f, 0.f, 0.f, 0.f, 0.f, 0.f};
  int j = beg;
  for (; j + 3 < end; j += 4) {
    int2 e0 = edges[j + 0];
    int2 e1 = edges[j + 1];
    int2 e2 = edges[j + 2];
    int2 e3 = edges[j + 3];
    uint4 r0 = ((const uint4*)(hin + e0.x))[fl];
    uint4 r1 = ((const uint4*)(hin + e1.x))[fl];
    uint4 r2 = ((const uint4*)(hin + e2.x))[fl];
    uint4 r3 = ((const uint4*)(hin + e3.x))[fl];
    fma8_h(acc, r0, __int_as_float(e0.y));
    fma8_h(acc, r1, __int_as_float(e1.y));
    fma8_h(acc, r2, __int_as_float(e2.y));
    fma8_h(acc, r3, __int_as_float(e3.y));
  }
  for (; j < end; ++j) {
    int2 e = edges[j];
    uint4 r = ((const uint4*)(hin + e.x))[fl];
    fma8_h(acc, r, __int_as_float(e.y));
  }

  if (OUT32) {
    float* op = (float*)hout + (size_t)node * OUT_F + 8 * fl;
    ((float4*)op)[0] = make_float4(acc[0], acc[1], acc[2], acc[3]);
    ((float4*)op)[1] = make_float4(acc[4], acc[5], acc[6], acc[7]);
  } else {
    union { __half2 h2[4]; uint4 u; } pk;
#pragma unroll
    for (int q = 0; q < 4; ++q)
      pk.h2[q] = __floats2half2_rn(acc[2 * q], acc[2 * q + 1]);
    ((uint4*)((char*)hout + (size_t)node * 128))[fl] = pk.u;
  }
}

extern "C" void kernel_launch(void* const* d_in, const int* in_sizes, int n_in,
                              void* d_out, int out_size, void* d_ws, size_t ws_size,
                              hipStream_t stream) {
  const float* x    = (const float*)d_in[0];
  const int*   ei   = (const int*)d_in[1];   // int32 (harness materializes ints as int32)
  const float* ew   = (const float*)d_in[2];
  const float* W    = (const float*)d_in[3];
  const float* bias = (const float*)d_in[4];
  float* out = (float*)d_out;

  const int N = N_NODES_C;
  const int E = N_EDGES_C;
  const int* src = ei;
  const int* dst = ei + E;
  const int NH = NBIN * NCHUNK;        // 50176 hist entries
  const int NRB = NH / RB;             // 196 reduce blocks

  char* p = (char*)d_ws;
  auto carve = [&](size_t bytes) {
    void* r = (void*)p;
    p += (bytes + 255) & ~(size_t)255;
    return r;
  };
  __half* h16A     = (__half*)carve((size_t)N * OUT_F * 2);
  __half* h16B     = (__half*)carve((size_t)N * OUT_F * 2);
  int*   row_ptr   = (int*)  carve((size_t)(N + 1) * 4);
  int2*  edges     = (int2*) carve((size_t)E * 8);
  int*   hist      = (int*)  carve((size_t)NH * 4);
  int*   soff      = (int*)  carve((size_t)NH * 4);
  int*   blockSums = (int*)  carve((size_t)NRB * 4);
  int*   blockOffs = (int*)  carve((size_t)NRB * 4);
  int*   binStart  = (int*)  carve((size_t)(NBIN + 1) * 4);  // +1 scratch for total

  // staging in d_out (free scratch until the final hop): sw 12.8MB + d 6.4MB
  int2* stage_sw = (int2*)d_out;
  int*  stage_d  = (int*)((char*)d_out + (size_t)E * 8);

  // CSR build (no global atomics)
  hist_kernel         <<<NCHUNK, 256, 0, stream>>>(dst, hist);
  reduce_kernel       <<<NRB, RB, 0, stream>>>(hist, blockSums, NH);
  scan_partials_kernel<<<1, 512, 0, stream>>>(blockSums, blockOffs, NRB, &binStart[NBIN]);
  scan_final_kernel   <<<NRB, RB, 0, stream>>>(hist, blockOffs, soff, binStart, NH);
  binscatter_kernel   <<<NCHUNK, 256, 0, stream>>>(src, dst, ew, soff, stage_d, stage_sw);
  place_kernel        <<<NBIN, BIN_SZ, 0, stream>>>(binStart, stage_d, stage_sw,
                                                    row_ptr, edges, N);

  // h0 = fp16(x @ W^T + b)
  gemm_kernel<<<(N + 63) / 64, 256, 0, stream>>>(x, W, bias, h16A, N);

  // 3 hops: fp16 -> fp16 -> fp16 -> fp32(out)
  spmm16_kernel<0><<<(N + 31) / 32, 256, 0, stream>>>(row_ptr, edges, h16A, h16B, N);
  spmm16_kernel<0><<<(N + 31) / 32, 256, 0, stream>>>(row_ptr, edges, h16B, h16A, N);
  spmm16_kernel<1><<<(N + 31) / 32, 256, 0, stream>>>(row_ptr, edges, h16A, out, N);
}

// Round 3
// 279.719 us; speedup vs baseline: 1.3325x; 1.0855x over previous
//
#include <hip/hip_runtime.h>
#include <hip/hip_fp16.h>

#define N_NODES_C 100000
#define N_EDGES_C 1600000
#define IN_F 128
#define OUT_F 64

#define BIN_SHIFT 9
#define BIN_SZ    512                                  // nodes per bin
#define NBIN      ((N_NODES_C + BIN_SZ - 1) / BIN_SZ)  // 196
#define NCHUNK    256
#define CH        (N_EDGES_C / NCHUNK)                 // 6250 exactly

typedef __attribute__((ext_vector_type(8))) _Float16 half8;
typedef __attribute__((ext_vector_type(4))) float    f32x4;

// ---------------- GEMM via MFMA: h[n][64] = fp16(x[n][128] @ W[64][128]^T + b) ----
// One wave per 16-node tile. B = W (row-major N=64 x K=128, i.e. B^T form) held as
// 16 register fragments (f16), converted once per wave. A loaded straight from
// global x (fp32 -> f16 in-register). 16 x mfma_f32_16x16x32_f16 per tile.
// Fragment maps (m89/m97-verified): A row=lane&15, k=(lane>>4)*8+i;
// B col=lane&15, same k map (common k-permutation cancels);
// D col=lane&15, row=(lane>>4)*4+reg.
__global__ __launch_bounds__(256) void gemm_mfma_kernel(
    const float* __restrict__ x, const float* __restrict__ W,
    const float* __restrict__ bias, _Float16* __restrict__ h, int n) {
  const int wid  = threadIdx.x >> 6;
  const int lane = threadIdx.x & 63;
  const int lr   = lane & 15;   // A-row / B-col / D-col
  const int lg   = lane >> 4;   // k-group (and D row-group)

  const int tile = blockIdx.x * 4 + wid;
  if (tile * 16 >= n) return;
  const int node0 = tile * 16;

  // ---- B fragments: bfrag[nc][kc], lane holds W[nc*16+lr][kc*32+lg*8 .. +7] ----
  half8 bfrag[4][4];
#pragma unroll
  for (int nc = 0; nc < 4; ++nc) {
    const float* wrow = W + (size_t)(nc * 16 + lr) * IN_F + lg * 8;
#pragma unroll
    for (int kc = 0; kc < 4; ++kc) {
      float4 a = ((const float4*)(wrow + kc * 32))[0];
      float4 b = ((const float4*)(wrow + kc * 32))[1];
      half8 f;
      f[0] = (_Float16)a.x; f[1] = (_Float16)a.y;
      f[2] = (_Float16)a.z; f[3] = (_Float16)a.w;
      f[4] = (_Float16)b.x; f[5] = (_Float16)b.y;
      f[6] = (_Float16)b.z; f[7] = (_Float16)b.w;
      bfrag[nc][kc] = f;
    }
  }

  // bias for this lane's output column in each nc-chunk
  float bv[4];
#pragma unroll
  for (int nc = 0; nc < 4; ++nc) bv[nc] = bias[nc * 16 + lr];

  // ---- A loads + MFMA ----
  const float* xp = x + (size_t)(node0 + lr) * IN_F + lg * 8;
  f32x4 acc[4] = {{0.f, 0.f, 0.f, 0.f}, {0.f, 0.f, 0.f, 0.f},
                  {0.f, 0.f, 0.f, 0.f}, {0.f, 0.f, 0.f, 0.f}};
#pragma unroll
  for (int kc = 0; kc < 4; ++kc) {
    float4 a = ((const float4*)(xp + kc * 32))[0];
    float4 b = ((const float4*)(xp + kc * 32))[1];
    half8 af;
    af[0] = (_Float16)a.x; af[1] = (_Float16)a.y;
    af[2] = (_Float16)a.z; af[3] = (_Float16)a.w;
    af[4] = (_Float16)b.x; af[5] = (_Float16)b.y;
    af[6] = (_Float16)b.z; af[7] = (_Float16)b.w;
#pragma unroll
    for (int nc = 0; nc < 4; ++nc)
      acc[nc] = __builtin_amdgcn_mfma_f32_16x16x32_f16(af, bfrag[nc][kc], acc[nc], 0, 0, 0);
  }

  // ---- store: D row = node0 + lg*4 + reg, col = nc*16 + lr ----
#pragma unroll
  for (int nc = 0; nc < 4; ++nc) {
#pragma unroll
    for (int r = 0; r < 4; ++r) {
      int node = node0 + lg * 4 + r;
      h[(size_t)node * OUT_F + nc * 16 + lr] = (_Float16)(acc[nc][r] + bv[nc]);
    }
  }
}

// ---------------- CSR build: LDS-binned counting sort ----------------
__global__ __launch_bounds__(256) void hist_kernel(
    const int* __restrict__ dst, int* __restrict__ hist) {
  __shared__ int h[NBIN];
  const int t = threadIdx.x;
  for (int i = t; i < NBIN; i += 256) h[i] = 0;
  __syncthreads();
  const int e0 = blockIdx.x * CH;
  for (int i = t; i < CH; i += 256)
    atomicAdd(&h[dst[e0 + i] >> BIN_SHIFT], 1);
  __syncthreads();
  for (int i = t; i < NBIN; i += 256)
    hist[i * NCHUNK + blockIdx.x] = h[i];      // bin-major layout
}

#define RB 256
__global__ __launch_bounds__(RB) void reduce_kernel(
    const int* __restrict__ v, int* __restrict__ blockSums, int n) {
  __shared__ int s[RB];
  int i = blockIdx.x * RB + threadIdx.x;
  s[threadIdx.x] = (i < n) ? v[i] : 0;
  __syncthreads();
  for (int off = RB / 2; off > 0; off >>= 1) {
    if (threadIdx.x < off) s[threadIdx.x] += s[threadIdx.x + off];
    __syncthreads();
  }
  if (threadIdx.x == 0) blockSums[blockIdx.x] = s[0];
}

__global__ __launch_bounds__(512) void scan_partials_kernel(
    const int* __restrict__ blockSums, int* __restrict__ blockOffs, int nb,
    int* __restrict__ total_out) {
  __shared__ int s[512];
  int t = threadIdx.x;
  int v = (t < nb) ? blockSums[t] : 0;
  s[t] = v;
  __syncthreads();
  for (int off = 1; off < 512; off <<= 1) {
    int u = (t >= off) ? s[t - off] : 0;
    __syncthreads();
    s[t] += u;
    __syncthreads();
  }
  if (t < nb) blockOffs[t] = s[t] - v;      // exclusive
  if (t == 511) *total_out = s[511];        // == E (scratch)
}

__global__ __launch_bounds__(RB) void scan_final_kernel(
    const int* __restrict__ hist, const int* __restrict__ blockOffs,
    int* __restrict__ soff, int* __restrict__ binStart, int n) {
  __shared__ int s[RB];
  int i = blockIdx.x * RB + threadIdx.x;
  int v = (i < n) ? hist[i] : 0;
  s[threadIdx.x] = v;
  __syncthreads();
  for (int off = 1; off < RB; off <<= 1) {
    int u = (threadIdx.x >= off) ? s[threadIdx.x - off] : 0;
    __syncthreads();
    s[threadIdx.x] += u;
    __syncthreads();
  }
  if (i < n) {
    int ex = blockOffs[blockIdx.x] + s[threadIdx.x] - v;
    soff[i] = ex;
    if (threadIdx.x == 0) binStart[blockIdx.x] = ex;   // chunk 0 of this bin
  }
}

__global__ __launch_bounds__(256) void binscatter_kernel(
    const int* __restrict__ src, const int* __restrict__ dst,
    const float* __restrict__ w, const int* __restrict__ soff,
    int* __restrict__ stage_d, int2* __restrict__ stage_sw) {
  __shared__ int lcur[NBIN];
  const int t = threadIdx.x;
  const int c = blockIdx.x;
  for (int i = t; i < NBIN; i += 256) lcur[i] = soff[i * NCHUNK + c];
  __syncthreads();
  const int e0 = c * CH;
  for (int i = t; i < CH; i += 256) {
    int e = e0 + i;
    int d = dst[e];
    int p = atomicAdd(&lcur[d >> BIN_SHIFT], 1);
    stage_d[p]  = d;
    stage_sw[p] = make_int2(src[e] * OUT_F, __float_as_int(w[e]));
  }
}

__global__ __launch_bounds__(BIN_SZ) void place_kernel(
    const int* __restrict__ binStart, const int* __restrict__ stage_d,
    const int2* __restrict__ stage_sw, int* __restrict__ row_ptr,
    int2* __restrict__ edges, int n) {
  __shared__ int lcount[BIN_SZ];
  __shared__ int s[BIN_SZ];
  __shared__ int lcur[BIN_SZ];
  const int t = threadIdx.x;
  const int b = blockIdx.x;
  const int base = binStart[b];
  const int end  = (b == NBIN - 1) ? N_EDGES_C : binStart[b + 1];
  const int node0 = b << BIN_SHIFT;

  lcount[t] = 0;
  __syncthreads();
  for (int i = base + t; i < end; i += BIN_SZ)
    atomicAdd(&lcount[stage_d[i] - node0], 1);
  __syncthreads();

  int v = lcount[t];
  s[t] = v;
  __syncthreads();
  for (int off = 1; off < BIN_SZ; off <<= 1) {
    int u = (t >= off) ? s[t - off] : 0;
    __syncthreads();
    s[t] += u;
    __syncthreads();
  }
  int ex = base + s[t] - v;       // exclusive CSR offset for node node0+t
  int node = node0 + t;
  if (node < n) row_ptr[node] = ex;
  lcur[t] = ex;
  __syncthreads();

  for (int i = base + t; i < end; i += BIN_SZ) {
    int d = stage_d[i];
    int p = atomicAdd(&lcur[d - node0], 1);
    edges[p] = stage_sw[i];
  }
  if (b == NBIN - 1 && t == 0) row_ptr[n] = N_EDGES_C;
}

// ---------------- SpMM hop (fp16 rows) ----------------
// 8 lanes per node (lane fl owns features [8fl..8fl+7]), 8 nodes per wave,
// 4-deep edge unroll. e.x = src*64 (element offset); fp16 row = 128 B.
__device__ inline void fma8_h(float* acc, uint4 r, float w) {
  unsigned u[4] = {r.x, r.y, r.z, r.w};
#pragma unroll
  for (int q = 0; q < 4; ++q) {
    __half2 h2 = *reinterpret_cast<__half2*>(&u[q]);
    float2 f = __half22float2(h2);
    acc[2 * q + 0] += w * f.x;
    acc[2 * q + 1] += w * f.y;
  }
}

template <int OUT32>
__global__ __launch_bounds__(256) void spmm16_kernel(
    const int* __restrict__ row_ptr, const int2* __restrict__ edges,
    const __half* __restrict__ hin, void* __restrict__ hout, int n) {
  const int node = blockIdx.x * 32 + (threadIdx.x >> 3);
  const int fl   = threadIdx.x & 7;     // feature octet
  if (node >= n) return;
  const int beg = row_ptr[node];
  const int end = row_ptr[node + 1];

  float acc[8] = {0.f, 0.f, 0.f, 0.f, 0.f, 0.f, 0.f, 0.f};
  int j = beg;
  for (; j + 3 < end; j += 4) {
    int2 e0 = edges[j + 0];
    int2 e1 = edges[j + 1];
    int2 e2 = edges[j + 2];
    int2 e3 = edges[j + 3];
    uint4 r0 = ((const uint4*)(hin + e0.x))[fl];
    uint4 r1 = ((const uint4*)(hin + e1.x))[fl];
    uint4 r2 = ((const uint4*)(hin + e2.x))[fl];
    uint4 r3 = ((const uint4*)(hin + e3.x))[fl];
    fma8_h(acc, r0, __int_as_float(e0.y));
    fma8_h(acc, r1, __int_as_float(e1.y));
    fma8_h(acc, r2, __int_as_float(e2.y));
    fma8_h(acc, r3, __int_as_float(e3.y));
  }
  for (; j < end; ++j) {
    int2 e = edges[j];
    uint4 r = ((const uint4*)(hin + e.x))[fl];
    fma8_h(acc, r, __int_as_float(e.y));
  }

  if (OUT32) {
    float* op = (float*)hout + (size_t)node * OUT_F + 8 * fl;
    ((float4*)op)[0] = make_float4(acc[0], acc[1], acc[2], acc[3]);
    ((float4*)op)[1] = make_float4(acc[4], acc[5], acc[6], acc[7]);
  } else {
    union { __half2 h2[4]; uint4 u; } pk;
#pragma unroll
    for (int q = 0; q < 4; ++q)
      pk.h2[q] = __floats2half2_rn(acc[2 * q], acc[2 * q + 1]);
    ((uint4*)((char*)hout + (size_t)node * 128))[fl] = pk.u;
  }
}

extern "C" void kernel_launch(void* const* d_in, const int* in_sizes, int n_in,
                              void* d_out, int out_size, void* d_ws, size_t ws_size,
                              hipStream_t stream) {
  const float* x    = (const float*)d_in[0];
  const int*   ei   = (const int*)d_in[1];   // int32 (harness materializes ints as int32)
  const float* ew   = (const float*)d_in[2];
  const float* W    = (const float*)d_in[3];
  const float* bias = (const float*)d_in[4];
  float* out = (float*)d_out;

  const int N = N_NODES_C;
  const int E = N_EDGES_C;
  const int* src = ei;
  const int* dst = ei + E;
  const int NH = NBIN * NCHUNK;        // 50176 hist entries
  const int NRB = NH / RB;             // 196 reduce blocks

  char* p = (char*)d_ws;
  auto carve = [&](size_t bytes) {
    void* r = (void*)p;
    p += (bytes + 255) & ~(size_t)255;
    return r;
  };
  __half* h16A     = (__half*)carve((size_t)N * OUT_F * 2);
  __half* h16B     = (__half*)carve((size_t)N * OUT_F * 2);
  int*   row_ptr   = (int*)  carve((size_t)(N + 1) * 4);
  int2*  edges     = (int2*) carve((size_t)E * 8);
  int*   hist      = (int*)  carve((size_t)NH * 4);
  int*   soff      = (int*)  carve((size_t)NH * 4);
  int*   blockSums = (int*)  carve((size_t)NRB * 4);
  int*   blockOffs = (int*)  carve((size_t)NRB * 4);
  int*   binStart  = (int*)  carve((size_t)(NBIN + 1) * 4);  // +1 scratch for total

  // staging in d_out (free scratch until the final hop): sw 12.8MB + d 6.4MB
  int2* stage_sw = (int2*)d_out;
  int*  stage_d  = (int*)((char*)d_out + (size_t)E * 8);

  // CSR build (no global atomics)
  hist_kernel         <<<NCHUNK, 256, 0, stream>>>(dst, hist);
  reduce_kernel       <<<NRB, RB, 0, stream>>>(hist, blockSums, NH);
  scan_partials_kernel<<<1, 512, 0, stream>>>(blockSums, blockOffs, NRB, &binStart[NBIN]);
  scan_final_kernel   <<<NRB, RB, 0, stream>>>(hist, blockOffs, soff, binStart, NH);
  binscatter_kernel   <<<NCHUNK, 256, 0, stream>>>(src, dst, ew, soff, stage_d, stage_sw);
  place_kernel        <<<NBIN, BIN_SZ, 0, stream>>>(binStart, stage_d, stage_sw,
                                                    row_ptr, edges, N);

  // h0 = fp16(x @ W^T + b) via MFMA
  gemm_mfma_kernel<<<(N / 16 + 3) / 4, 256, 0, stream>>>(x, W, bias, (_Float16*)h16A, N);

  // 3 hops: fp16 -> fp16 -> fp16 -> fp32(out)
  spmm16_kernel<0><<<(N + 31) / 32, 256, 0, stream>>>(row_ptr, edges, h16A, h16B, N);
  spmm16_kernel<0><<<(N + 31) / 32, 256, 0, stream>>>(row_ptr, edges, h16B, h16A, N);
  spmm16_kernel<1><<<(N + 31) / 32, 256, 0, stream>>>(row_ptr, edges, h16A, out, N);
}

// Round 4
// 270.210 us; speedup vs baseline: 1.3793x; 1.0352x over previous
//
#include <hip/hip_runtime.h>
#include <hip/hip_fp16.h>

#define N_NODES_C 100000
#define N_EDGES_C 1600000
#define IN_F 128
#define OUT_F 64

#define BIN_SHIFT 9
#define BIN_SZ    512                                  // nodes per bin
#define NBIN      ((N_NODES_C + BIN_SZ - 1) / BIN_SZ)  // 196
#define NCHUNK    256
#define CH        (N_EDGES_C / NCHUNK)                 // 6250 exactly

typedef __attribute__((ext_vector_type(8))) _Float16 half8;
typedef __attribute__((ext_vector_type(4))) float    f32x4;

// ---------------- GEMM via MFMA: h[n][64] = fp16(x[n][128] @ W[64][128]^T + b) ----
// One wave per 16-node tile. B = W (row-major N=64 x K=128, i.e. B^T form) held as
// 16 register fragments (f16), converted once per wave. A loaded straight from
// global x (fp32 -> f16 in-register). 16 x mfma_f32_16x16x32_f16 per tile.
// Fragment maps (m89/m97-verified): A row=lane&15, k=(lane>>4)*8+i;
// B col=lane&15, same k map (common k-permutation cancels);
// D col=lane&15, row=(lane>>4)*4+reg.
__global__ __launch_bounds__(256) void gemm_mfma_kernel(
    const float* __restrict__ x, const float* __restrict__ W,
    const float* __restrict__ bias, _Float16* __restrict__ h, int n) {
  const int wid  = threadIdx.x >> 6;
  const int lane = threadIdx.x & 63;
  const int lr   = lane & 15;   // A-row / B-col / D-col
  const int lg   = lane >> 4;   // k-group (and D row-group)

  const int tile = blockIdx.x * 4 + wid;
  if (tile * 16 >= n) return;
  const int node0 = tile * 16;

  // ---- B fragments: bfrag[nc][kc], lane holds W[nc*16+lr][kc*32+lg*8 .. +7] ----
  half8 bfrag[4][4];
#pragma unroll
  for (int nc = 0; nc < 4; ++nc) {
    const float* wrow = W + (size_t)(nc * 16 + lr) * IN_F + lg * 8;
#pragma unroll
    for (int kc = 0; kc < 4; ++kc) {
      float4 a = ((const float4*)(wrow + kc * 32))[0];
      float4 b = ((const float4*)(wrow + kc * 32))[1];
      half8 f;
      f[0] = (_Float16)a.x; f[1] = (_Float16)a.y;
      f[2] = (_Float16)a.z; f[3] = (_Float16)a.w;
      f[4] = (_Float16)b.x; f[5] = (_Float16)b.y;
      f[6] = (_Float16)b.z; f[7] = (_Float16)b.w;
      bfrag[nc][kc] = f;
    }
  }

  // bias for this lane's output column in each nc-chunk
  float bv[4];
#pragma unroll
  for (int nc = 0; nc < 4; ++nc) bv[nc] = bias[nc * 16 + lr];

  // ---- A loads + MFMA ----
  const float* xp = x + (size_t)(node0 + lr) * IN_F + lg * 8;
  f32x4 acc[4] = {{0.f, 0.f, 0.f, 0.f}, {0.f, 0.f, 0.f, 0.f},
                  {0.f, 0.f, 0.f, 0.f}, {0.f, 0.f, 0.f, 0.f}};
#pragma unroll
  for (int kc = 0; kc < 4; ++kc) {
    float4 a = ((const float4*)(xp + kc * 32))[0];
    float4 b = ((const float4*)(xp + kc * 32))[1];
    half8 af;
    af[0] = (_Float16)a.x; af[1] = (_Float16)a.y;
    af[2] = (_Float16)a.z; af[3] = (_Float16)a.w;
    af[4] = (_Float16)b.x; af[5] = (_Float16)b.y;
    af[6] = (_Float16)b.z; af[7] = (_Float16)b.w;
#pragma unroll
    for (int nc = 0; nc < 4; ++nc)
      acc[nc] = __builtin_amdgcn_mfma_f32_16x16x32_f16(af, bfrag[nc][kc], acc[nc], 0, 0, 0);
  }

  // ---- store: D row = node0 + lg*4 + reg, col = nc*16 + lr ----
#pragma unroll
  for (int nc = 0; nc < 4; ++nc) {
#pragma unroll
    for (int r = 0; r < 4; ++r) {
      int node = node0 + lg * 4 + r;
      h[(size_t)node * OUT_F + nc * 16 + lr] = (_Float16)(acc[nc][r] + bv[nc]);
    }
  }
}

// ---------------- CSR build: LDS-binned counting sort ----------------
// Phase 1: per-chunk LDS histogram over 196 bins. 1024 threads: the loop is
// latency-bound (dependent load->LDS-atomic), 16 waves/CU hides it.
__global__ __launch_bounds__(1024) void hist_kernel(
    const int* __restrict__ dst, int* __restrict__ hist) {
  __shared__ int h[NBIN];
  const int t = threadIdx.x;
  for (int i = t; i < NBIN; i += 1024) h[i] = 0;
  __syncthreads();
  const int e0 = blockIdx.x * CH;
  for (int i = t; i < CH; i += 1024)
    atomicAdd(&h[dst[e0 + i] >> BIN_SHIFT], 1);
  __syncthreads();
  for (int i = t; i < NBIN; i += 1024)
    hist[i * NCHUNK + blockIdx.x] = h[i];      // bin-major layout
}

#define RB 256
__global__ __launch_bounds__(RB) void reduce_kernel(
    const int* __restrict__ v, int* __restrict__ blockSums, int n) {
  __shared__ int s[RB];
  int i = blockIdx.x * RB + threadIdx.x;
  s[threadIdx.x] = (i < n) ? v[i] : 0;
  __syncthreads();
  for (int off = RB / 2; off > 0; off >>= 1) {
    if (threadIdx.x < off) s[threadIdx.x] += s[threadIdx.x + off];
    __syncthreads();
  }
  if (threadIdx.x == 0) blockSums[blockIdx.x] = s[0];
}

__global__ __launch_bounds__(512) void scan_partials_kernel(
    const int* __restrict__ blockSums, int* __restrict__ blockOffs, int nb,
    int* __restrict__ total_out) {
  __shared__ int s[512];
  int t = threadIdx.x;
  int v = (t < nb) ? blockSums[t] : 0;
  s[t] = v;
  __syncthreads();
  for (int off = 1; off < 512; off <<= 1) {
    int u = (t >= off) ? s[t - off] : 0;
    __syncthreads();
    s[t] += u;
    __syncthreads();
  }
  if (t < nb) blockOffs[t] = s[t] - v;      // exclusive
  if (t == 511) *total_out = s[511];        // == E (scratch)
}

__global__ __launch_bounds__(RB) void scan_final_kernel(
    const int* __restrict__ hist, const int* __restrict__ blockOffs,
    int* __restrict__ soff, int* __restrict__ binStart, int n) {
  __shared__ int s[RB];
  int i = blockIdx.x * RB + threadIdx.x;
  int v = (i < n) ? hist[i] : 0;
  s[threadIdx.x] = v;
  __syncthreads();
  for (int off = 1; off < RB; off <<= 1) {
    int u = (threadIdx.x >= off) ? s[threadIdx.x - off] : 0;
    __syncthreads();
    s[threadIdx.x] += u;
    __syncthreads();
  }
  if (i < n) {
    int ex = blockOffs[blockIdx.x] + s[threadIdx.x] - v;
    soff[i] = ex;
    if (threadIdx.x == 0) binStart[blockIdx.x] = ex;   // chunk 0 of this bin
  }
}

// Phase 2: re-read chunk, append records at LDS-cursor positions. 1024 threads
// (was 256: 6.6% occupancy, 0.85% VALUBusy -> pure latency starvation).
__global__ __launch_bounds__(1024) void binscatter_kernel(
    const int* __restrict__ src, const int* __restrict__ dst,
    const float* __restrict__ w, const int* __restrict__ soff,
    int* __restrict__ stage_d, int2* __restrict__ stage_sw) {
  __shared__ int lcur[NBIN];
  const int t = threadIdx.x;
  const int c = blockIdx.x;
  for (int i = t; i < NBIN; i += 1024) lcur[i] = soff[i * NCHUNK + c];
  __syncthreads();
  const int e0 = c * CH;
  for (int i = t; i < CH; i += 1024) {
    int e = e0 + i;
    int d = dst[e];
    int p = atomicAdd(&lcur[d >> BIN_SHIFT], 1);
    stage_d[p]  = d;
    stage_sw[p] = make_int2(src[e] * OUT_F, __float_as_int(w[e]));
  }
}

// Phase 3: one block per bin, 1024 threads. Scan phase restricted to t<BIN_SZ
// (all threads reach every barrier); count/place loops use all 1024.
__global__ __launch_bounds__(1024) void place_kernel(
    const int* __restrict__ binStart, const int* __restrict__ stage_d,
    const int2* __restrict__ stage_sw, int* __restrict__ row_ptr,
    int2* __restrict__ edges, int n) {
  __shared__ int lcount[BIN_SZ];
  __shared__ int s[BIN_SZ];
  __shared__ int lcur[BIN_SZ];
  const int t = threadIdx.x;
  const int b = blockIdx.x;
  const int base = binStart[b];
  const int end  = (b == NBIN - 1) ? N_EDGES_C : binStart[b + 1];
  const int node0 = b << BIN_SHIFT;

  if (t < BIN_SZ) lcount[t] = 0;
  __syncthreads();
  for (int i = base + t; i < end; i += 1024)
    atomicAdd(&lcount[stage_d[i] - node0], 1);
  __syncthreads();

  int v = 0;
  if (t < BIN_SZ) { v = lcount[t]; s[t] = v; }
  __syncthreads();
  for (int off = 1; off < BIN_SZ; off <<= 1) {
    int u = (t < BIN_SZ && t >= off) ? s[t - off] : 0;
    __syncthreads();
    if (t < BIN_SZ) s[t] += u;
    __syncthreads();
  }
  if (t < BIN_SZ) {
    int ex = base + s[t] - v;     // exclusive CSR offset for node node0+t
    int node = node0 + t;
    if (node < n) row_ptr[node] = ex;
    lcur[t] = ex;
  }
  __syncthreads();

  for (int i = base + t; i < end; i += 1024) {
    int d = stage_d[i];
    int p = atomicAdd(&lcur[d - node0], 1);
    edges[p] = stage_sw[i];
  }
  if (b == NBIN - 1 && t == 0) row_ptr[n] = N_EDGES_C;
}

// ---------------- SpMM hop (fp16 rows) ----------------
// 8 lanes per node (lane fl owns features [8fl..8fl+7]), 8 nodes per wave,
// 4-deep edge unroll. e.x = src*64 (element offset); fp16 row = 128 B.
__device__ inline void fma8_h(float* acc, uint4 r, float w) {
  unsigned u[4] = {r.x, r.y, r.z, r.w};
#pragma unroll
  for (int q = 0; q < 4; ++q) {
    __half2 h2 = *reinterpret_cast<__half2*>(&u[q]);
    float2 f = __half22float2(h2);
    acc[2 * q + 0] += w * f.x;
    acc[2 * q + 1] += w * f.y;
  }
}

template <int OUT32>
__global__ __launch_bounds__(256) void spmm16_kernel(
    const int* __restrict__ row_ptr, const int2* __restrict__ edges,
    const __half* __restrict__ hin, void* __restrict__ hout, int n) {
  const int node = blockIdx.x * 32 + (threadIdx.x >> 3);
  const int fl   = threadIdx.x & 7;     // feature octet
  if (node >= n) return;
  const int beg = row_ptr[node];
  const int end = row_ptr[node + 1];

  float acc[8] = {0.f, 0.f, 0.f, 0.f, 0.f, 0.f, 0.f, 0.f};
  int j = beg;
  for (; j + 3 < end; j += 4) {
    int2 e0 = edges[j + 0];
    int2 e1 = edges[j + 1];
    int2 e2 = edges[j + 2];
    int2 e3 = edges[j + 3];
    uint4 r0 = ((const uint4*)(hin + e0.x))[fl];
    uint4 r1 = ((const uint4*)(hin + e1.x))[fl];
    uint4 r2 = ((const uint4*)(hin + e2.x))[fl];
    uint4 r3 = ((const uint4*)(hin + e3.x))[fl];
    fma8_h(acc, r0, __int_as_float(e0.y));
    fma8_h(acc, r1, __int_as_float(e1.y));
    fma8_h(acc, r2, __int_as_float(e2.y));
    fma8_h(acc, r3, __int_as_float(e3.y));
  }
  for (; j < end; ++j) {
    int2 e = edges[j];
    uint4 r = ((const uint4*)(hin + e.x))[fl];
    fma8_h(acc, r, __int_as_float(e.y));
  }

  if (OUT32) {
    float* op = (float*)hout + (size_t)node * OUT_F + 8 * fl;
    ((float4*)op)[0] = make_float4(acc[0], acc[1], acc[2], acc[3]);
    ((float4*)op)[1] = make_float4(acc[4], acc[5], acc[6], acc[7]);
  } else {
    union { __half2 h2[4]; uint4 u; } pk;
#pragma unroll
    for (int q = 0; q < 4; ++q)
      pk.h2[q] = __floats2half2_rn(acc[2 * q], acc[2 * q + 1]);
    ((uint4*)((char*)hout + (size_t)node * 128))[fl] = pk.u;
  }
}

extern "C" void kernel_launch(void* const* d_in, const int* in_sizes, int n_in,
                              void* d_out, int out_size, void* d_ws, size_t ws_size,
                              hipStream_t stream) {
  const float* x    = (const float*)d_in[0];
  const int*   ei   = (const int*)d_in[1];   // int32 (harness materializes ints as int32)
  const float* ew   = (const float*)d_in[2];
  const float* W    = (const float*)d_in[3];
  const float* bias = (const float*)d_in[4];
  float* out = (float*)d_out;

  const int N = N_NODES_C;
  const int E = N_EDGES_C;
  const int* src = ei;
  const int* dst = ei + E;
  const int NH = NBIN * NCHUNK;        // 50176 hist entries
  const int NRB = NH / RB;             // 196 reduce blocks

  char* p = (char*)d_ws;
  auto carve = [&](size_t bytes) {
    void* r = (void*)p;
    p += (bytes + 255) & ~(size_t)255;
    return r;
  };
  __half* h16A     = (__half*)carve((size_t)N * OUT_F * 2);
  __half* h16B     = (__half*)carve((size_t)N * OUT_F * 2);
  int*   row_ptr   = (int*)  carve((size_t)(N + 1) * 4);
  int2*  edges     = (int2*) carve((size_t)E * 8);
  int*   hist      = (int*)  carve((size_t)NH * 4);
  int*   soff      = (int*)  carve((size_t)NH * 4);
  int*   blockSums = (int*)  carve((size_t)NRB * 4);
  int*   blockOffs = (int*)  carve((size_t)NRB * 4);
  int*   binStart  = (int*)  carve((size_t)(NBIN + 1) * 4);  // +1 scratch for total

  // staging in d_out (free scratch until the final hop): sw 12.8MB + d 6.4MB
  int2* stage_sw = (int2*)d_out;
  int*  stage_d  = (int*)((char*)d_out + (size_t)E * 8);

  // CSR build (no global atomics)
  hist_kernel         <<<NCHUNK, 1024, 0, stream>>>(dst, hist);
  reduce_kernel       <<<NRB, RB, 0, stream>>>(hist, blockSums, NH);
  scan_partials_kernel<<<1, 512, 0, stream>>>(blockSums, blockOffs, NRB, &binStart[NBIN]);
  scan_final_kernel   <<<NRB, RB, 0, stream>>>(hist, blockOffs, soff, binStart, NH);
  binscatter_kernel   <<<NCHUNK, 1024, 0, stream>>>(src, dst, ew, soff, stage_d, stage_sw);
  place_kernel        <<<NBIN, 1024, 0, stream>>>(binStart, stage_d, stage_sw,
                                                  row_ptr, edges, N);

  // h0 = fp16(x @ W^T + b) via MFMA
  gemm_mfma_kernel<<<(N / 16 + 3) / 4, 256, 0, stream>>>(x, W, bias, (_Float16*)h16A, N);

  // 3 hops: fp16 -> fp16 -> fp16 -> fp32(out)
  spmm16_kernel<0><<<(N + 31) / 32, 256, 0, stream>>>(row_ptr, edges, h16A, h16B, N);
  spmm16_kernel<0><<<(N + 31) / 32, 256, 0, stream>>>(row_ptr, edges, h16B, h16A, N);
  spmm16_kernel<1><<<(N + 31) / 32, 256, 0, stream>>>(row_ptr, edges, h16A, out, N);
}